// Round 7
// baseline (249.226 us; speedup 1.0000x reference)
//
#include <hip/hip_runtime.h>
#include <math.h>

#define NB 4
#define NN 512

// ---------------- kA: ha = X@Wa + b1, hb = X@Wb ; zero ru + bar ----------
__global__ void kA(const float* __restrict__ X, const float* __restrict__ W1,
                   const float* __restrict__ b1, float* __restrict__ ha,
                   float* __restrict__ hb, float* __restrict__ ru,
                   unsigned* __restrict__ bar) {
  int b = blockIdx.y, n0 = blockIdx.x * 8;
  __shared__ float xs[8][128];
  int t = threadIdx.x;  // 128 threads
  for (int q = t; q < 1024; q += 128) {
    int r = q >> 7, f = q & 127;
    xs[r][f] = X[(size_t)(b * NN + n0 + r) * 128 + f];
  }
  int flat = b * 64 + blockIdx.x;
  if (flat < 16) ru[flat * 128 + t] = 0.f;
  if (flat == 16 && t < 16) bar[t] = 0u;
  __syncthreads();
  float accA[8] = {0,0,0,0,0,0,0,0}, accB[8] = {0,0,0,0,0,0,0,0};
  for (int f = 0; f < 128; ++f) {
    float wa = W1[f * 128 + t];
    float wb = W1[(128 + f) * 128 + t];
#pragma unroll
    for (int r = 0; r < 8; ++r) {
      accA[r] = fmaf(xs[r][f], wa, accA[r]);
      accB[r] = fmaf(xs[r][f], wb, accB[r]);
    }
  }
  float b1v = b1[t];
#pragma unroll
  for (int r = 0; r < 8; ++r) {
    ha[(size_t)(b * NN + n0 + r) * 128 + t] = accA[r] + b1v;
    hb[(size_t)(b * NN + n0 + r) * 128 + t] = accB[r];
  }
}

// ------- kB: K = exp(-5*cost), cost = relu(ha_i+hb_j+dist*wd)@W2 + b2 ----
__global__ void kB(const float* __restrict__ ha, const float* __restrict__ hb,
                   const float* __restrict__ coords, const float* __restrict__ W1,
                   const float* __restrict__ W2, const float* __restrict__ b2,
                   float* __restrict__ Km, float* __restrict__ ru) {
  int b = blockIdx.z, i0 = blockIdx.y * 32, j0 = blockIdx.x * 32;
  __shared__ alignas(16) float As[32][132];
  __shared__ alignas(16) float Bs[32][132];
  __shared__ alignas(16) float wd[128];
  __shared__ alignas(16) float w2[128];
  __shared__ float ci[32][3], cj[32][3];
  int t = threadIdx.x;  // 256
  for (int q = t; q < 1024; q += 256) {
    int r = q >> 5, c = (q & 31) * 4;
    *(float4*)&As[r][c] = *(const float4*)&ha[(size_t)(b * NN + i0 + r) * 128 + c];
    *(float4*)&Bs[r][c] = *(const float4*)&hb[(size_t)(b * NN + j0 + r) * 128 + c];
  }
  if (t < 128) { wd[t] = W1[256 * 128 + t]; w2[t] = W2[t]; }
  if (t < 96) ((float*)ci)[t] = coords[(size_t)(b * NN + i0) * 3 + t];
  else if (t < 192) ((float*)cj)[t - 96] = coords[(size_t)(b * NN + j0) * 3 + (t - 96)];
  __syncthreads();
  int tx = t & 15, ty = t >> 4;
  int ia = 2 * ty, ib = ia + 1, ja = tx, jb = tx + 16;
  float d00, d01, d10, d11;
  {
    float ax = ci[ia][0], ay = ci[ia][1], az = ci[ia][2];
    float bx = ci[ib][0], by = ci[ib][1], bz = ci[ib][2];
    float cx0 = cj[ja][0], cy0 = cj[ja][1], cz0 = cj[ja][2];
    float cx1 = cj[jb][0], cy1 = cj[jb][1], cz1 = cj[jb][2];
    float dx, dy, dz;
    dx = ax - cx0; dy = ay - cy0; dz = az - cz0;
    d00 = sqrtf(fmaxf(dx * dx + dy * dy + dz * dz, 0.f));
    dx = ax - cx1; dy = ay - cy1; dz = az - cz1;
    d01 = sqrtf(fmaxf(dx * dx + dy * dy + dz * dz, 0.f));
    dx = bx - cx0; dy = by - cy0; dz = bz - cz0;
    d10 = sqrtf(fmaxf(dx * dx + dy * dy + dz * dz, 0.f));
    dx = bx - cx1; dy = by - cy1; dz = bz - cz1;
    d11 = sqrtf(fmaxf(dx * dx + dy * dy + dz * dz, 0.f));
  }
  float a00 = 0, a01 = 0, a10 = 0, a11 = 0;
  for (int k = 0; k < 128; k += 4) {
    float4 A0 = *(float4*)&As[ia][k];
    float4 A1 = *(float4*)&As[ib][k];
    float4 B0 = *(float4*)&Bs[ja][k];
    float4 B1 = *(float4*)&Bs[jb][k];
    float4 W = *(float4*)&wd[k];
    float4 V = *(float4*)&w2[k];
#pragma unroll
    for (int kk = 0; kk < 4; ++kk) {
      float av = ((float*)&A0)[kk], av1 = ((float*)&A1)[kk];
      float bv = ((float*)&B0)[kk], bv1 = ((float*)&B1)[kk];
      float wv = ((float*)&W)[kk], vv = ((float*)&V)[kk];
      float t00 = fmaxf(fmaf(d00, wv, av + bv), 0.f);
      float t01 = fmaxf(fmaf(d01, wv, av + bv1), 0.f);
      float t10 = fmaxf(fmaf(d10, wv, av1 + bv), 0.f);
      float t11 = fmaxf(fmaf(d11, wv, av1 + bv1), 0.f);
      a00 = fmaf(t00, vv, a00);
      a01 = fmaf(t01, vv, a01);
      a10 = fmaf(t10, vv, a10);
      a11 = fmaf(t11, vv, a11);
    }
  }
  float b2v = b2[0];
  float k00 = __expf(-5.0f * (a00 + b2v));
  float k01 = __expf(-5.0f * (a01 + b2v));
  float k10 = __expf(-5.0f * (a10 + b2v));
  float k11 = __expf(-5.0f * (a11 + b2v));
  size_t r0 = (size_t)(b * NN + i0 + ia) * NN + j0;
  size_t r1 = (size_t)(b * NN + i0 + ib) * NN + j0;
  Km[r0 + ja] = k00; Km[r0 + jb] = k01;
  Km[r1 + ja] = k10; Km[r1 + jb] = k11;
  float s0 = k00 + k01, s1 = k10 + k11;
#pragma unroll
  for (int off = 1; off < 16; off <<= 1) {
    s0 += __shfl_xor(s0, off);
    s1 += __shfl_xor(s1, off);
  }
  if (tx == 0) {
    atomicAdd(&ru[b * NN + i0 + ia], s0);
    atomicAdd(&ru[b * NN + i0 + ib], s1);
  }
}

// ------- device-wide barrier (64 blocks, all resident) -------------------
__device__ inline void gbar(unsigned* bar, int slot) {
  __syncthreads();
  if (threadIdx.x == 0) {
    __threadfence();
    __hip_atomic_fetch_add(&bar[slot], 1u, __ATOMIC_RELEASE, __HIP_MEMORY_SCOPE_AGENT);
    while (__hip_atomic_load(&bar[slot], __ATOMIC_ACQUIRE, __HIP_MEMORY_SCOPE_AGENT) < 64u) {
      __builtin_amdgcn_s_sleep(8);
    }
    __threadfence();
  }
  __syncthreads();
}

// ------- kSink2: fully fused Sinkhorn, manual global barrier -------------
// grid (16,4): block (ic,b) owns rows ic*32..+32 of batch b. ru = K row sums.
__global__ __launch_bounds__(512) void kSink2(const float* __restrict__ Km,
                                              const float* __restrict__ ru,
                                              float* __restrict__ rvpA,
                                              float* __restrict__ rvpB,
                                              float* __restrict__ out,
                                              unsigned* __restrict__ bar) {
  int ic = blockIdx.x, b = blockIdx.y;
  int t = threadIdx.x;  // 512
  int r0 = ic * 32;
  __shared__ float vinv[512];
  __shared__ float uinv[32];
  const float* Kcp = Km + (size_t)(b * NN + r0) * NN + t;
  // step 0: uinv = u1 (from kB row sums); col partials -> rvpA
  if (t < 32) uinv[t] = 1.0f / ru[b * NN + r0 + t];
  __syncthreads();
  {
    float acc = 0.f;
#pragma unroll 8
    for (int ii = 0; ii < 32; ++ii) acc = fmaf(Kcp[(size_t)ii * NN], uinv[ii], acc);
    __hip_atomic_store(&rvpA[ic * 2048 + b * NN + t], acc,
                       __ATOMIC_RELAXED, __HIP_MEMORY_SCOPE_AGENT);
  }
  gbar(bar, 0);
  float* rsrc = rvpA;
  float* rdst = rvpB;
  for (int it = 0; it < 9; ++it) {
    // vinv from all 16 slabs (agent-scope loads: cross-XCD fresh)
    {
      float s = 0.f;
#pragma unroll
      for (int q = 0; q < 16; ++q)
        s += __hip_atomic_load(&rsrc[q * 2048 + b * NN + t],
                               __ATOMIC_RELAXED, __HIP_MEMORY_SCOPE_AGENT);
      vinv[t] = 1.0f / s;
    }
    __syncthreads();
    // row pass: 8 waves x 4 rows
    int w = t >> 6, l = t & 63;
#pragma unroll
    for (int m = 0; m < 4; ++m) {
      int r = r0 + w * 4 + m;
      const float* Kp = Km + (size_t)(b * NN + r) * NN;
      float acc = 0.f;
#pragma unroll
      for (int mm = 0; mm < 8; ++mm) acc = fmaf(Kp[l + 64 * mm], vinv[l + 64 * mm], acc);
#pragma unroll
      for (int off = 1; off < 64; off <<= 1) acc += __shfl_xor(acc, off);
      if (l == 0) uinv[w * 4 + m] = 1.0f / acc;
    }
    __syncthreads();
    // col partials with new uinv
    {
      float acc = 0.f;
#pragma unroll 8
      for (int ii = 0; ii < 32; ++ii) acc = fmaf(Kcp[(size_t)ii * NN], uinv[ii], acc);
      __hip_atomic_store(&rdst[ic * 2048 + b * NN + t], acc,
                         __ATOMIC_RELAXED, __HIP_MEMORY_SCOPE_AGENT);
    }
    gbar(bar, 1 + it);
    float* tmp = rsrc; rsrc = rdst; rdst = tmp;
  }
  // epilogue: adj = uinv_i * K * vinv_j (u10, v10)
  {
    float s = 0.f;
#pragma unroll
    for (int q = 0; q < 16; ++q)
      s += __hip_atomic_load(&rsrc[q * 2048 + b * NN + t],
                             __ATOMIC_RELAXED, __HIP_MEMORY_SCOPE_AGENT);
    float vj = 1.0f / s;
    const float* Kp = Km + (size_t)(b * NN + r0) * NN + t;
    float* op = out + (size_t)(b * NN + r0) * NN + t;
#pragma unroll 4
    for (int m = 0; m < 32; ++m)
      op[(size_t)m * NN] = Kp[(size_t)m * NN] * uinv[m] * vj;
  }
}

// ------- kG1f: xw = x @ Wg[l] + fused s_src/s_dst epilogue ---------------
__global__ void kG1f(const float* __restrict__ x, const float* __restrict__ Wg,
                     const float* __restrict__ asrc, const float* __restrict__ adst,
                     float* __restrict__ xw, float* __restrict__ ssT,
                     float* __restrict__ sdT) {
  int b = blockIdx.y, n0 = blockIdx.x * 8;
  __shared__ float xs[8][128];
  __shared__ float red[4][8][4];  // wave, r, {s_c0, d_c0, s_c1, d_c1}
  int t = threadIdx.x;  // 256
  for (int q = t; q < 1024; q += 256) {
    int r = q >> 7, f = q & 127;
    xs[r][f] = x[(size_t)(b * NN + n0 + r) * 128 + f];
  }
  __syncthreads();
  int c0 = t, c1 = t + 256;
  float acc0[8] = {0,0,0,0,0,0,0,0}, acc1[8] = {0,0,0,0,0,0,0,0};
  for (int f = 0; f < 128; ++f) {
    float w0 = Wg[f * 512 + c0], w1 = Wg[f * 512 + c1];
#pragma unroll
    for (int r = 0; r < 8; ++r) {
      float xv = xs[r][f];
      acc0[r] = fmaf(xv, w0, acc0[r]);
      acc1[r] = fmaf(xv, w1, acc1[r]);
    }
  }
#pragma unroll
  for (int r = 0; r < 8; ++r) {
    xw[(size_t)(b * NN + n0 + r) * 512 + c0] = acc0[r];
    xw[(size_t)(b * NN + n0 + r) * 512 + c1] = acc1[r];
  }
  float as0 = asrc[c0], ad0 = adst[c0];
  float as1 = asrc[c1], ad1 = adst[c1];
  int w = t >> 6, l = t & 63;
#pragma unroll
  for (int r = 0; r < 8; ++r) {
    float ps0 = acc0[r] * as0, pd0 = acc0[r] * ad0;
    float ps1 = acc1[r] * as1, pd1 = acc1[r] * ad1;
#pragma unroll
    for (int off = 1; off < 64; off <<= 1) {
      ps0 += __shfl_xor(ps0, off);
      pd0 += __shfl_xor(pd0, off);
      ps1 += __shfl_xor(ps1, off);
      pd1 += __shfl_xor(pd1, off);
    }
    if (l == 0) {
      red[w][r][0] = ps0; red[w][r][1] = pd0;
      red[w][r][2] = ps1; red[w][r][3] = pd1;
    }
  }
  __syncthreads();
  if (t < 64) {
    int r = t & 7, h = (t >> 3) & 3, sd = t >> 5;
    int wbase = (h & 1) ? 2 : 0;
    int which = (h < 2 ? 0 : 2) + sd;
    float s = red[wbase][r][which] + red[wbase + 1][r][which];
    float* dst = sd ? sdT : ssT;
    dst[(size_t)(b * 4 + h) * 512 + n0 + r] = s;
  }
}

// ------- kG2m: per (b, 8-row tile): all 4 heads + bg, writes x directly --
#define PLD8 520
__global__ __launch_bounds__(512) void kG2m(const float* __restrict__ xw,
                                            const float* __restrict__ ssT,
                                            const float* __restrict__ sdT,
                                            const float* __restrict__ bg,
                                            float* __restrict__ xo) {
  int b = blockIdx.y, i0 = blockIdx.x * 8;
  __shared__ float ss4[4][512];
  __shared__ alignas(16) float pl[8][PLD8];   // reused as reduce scratch
  __shared__ float sdl[4][8], smax[4], mxl[8], idl[8];
  __shared__ float smaxsh[4][8];
  int t = threadIdx.x;  // 512
  // load ss for all 4 heads + per-head per-wave maxes
#pragma unroll
  for (int q = 0; q < 4; ++q) {
    float v = ssT[(size_t)(b * 4 + q) * 512 + t];
    ss4[q][t] = v;
#pragma unroll
    for (int off = 1; off < 64; off <<= 1) v = fmaxf(v, __shfl_xor(v, off));
    if ((t & 63) == 0) smaxsh[q][t >> 6] = v;
  }
  if (t < 32) {
    int h = t >> 3, r = t & 7;
    sdl[h][r] = sdT[(size_t)(b * 4 + h) * 512 + i0 + r];
  }
  __syncthreads();
  if (t < 4) {
    float m = smaxsh[t][0];
#pragma unroll
    for (int q = 1; q < 8; ++q) m = fmaxf(m, smaxsh[t][q]);
    smax[t] = m;
  }
  int fq = t & 31, rr = (t >> 5) & 3, jh = t >> 7;
  float4 osum = {0, 0, 0, 0};
  for (int h = 0; h < 4; ++h) {
    __syncthreads();  // protects: smax ready (h=0); prev sc4 reads done; idl/mxl reuse
    if (t < 8) {
      float mm = sdl[h][t] + smax[h];
      mxl[t] = (mm >= 0.f) ? mm : 0.2f * mm;
    }
    __syncthreads();
    // phase A
    {
      int il = t >> 6, jq = t & 63;
      float mx = mxl[il], sdv = sdl[h][il];
      float den = 0.f;
#pragma unroll
      for (int jj = 0; jj < 8; ++jj) {
        int j = jj * 64 + jq;
        float e = sdv + ss4[h][j];
        e = (e >= 0.f) ? e : 0.2f * e;
        float pe = __expf(e - mx);
        pl[il][j] = pe;
        den += pe;
      }
#pragma unroll
      for (int off = 1; off < 64; off <<= 1) den += __shfl_xor(den, off);
      if (jq == 0) idl[il] = 1.0f / (4.0f * den);
    }
    __syncthreads();
    // phase B: rows rr, rr+4; j-quarter jh
    const float* xp = xw + (size_t)(b * NN) * 512 + h * 128 + fq * 4;
    float4 a0 = {0,0,0,0}, a1 = {0,0,0,0};
    int jbase = jh * 128;
#pragma unroll 4
    for (int jj = 0; jj < 128; jj += 2) {
      int j = jbase + jj;
      float4 xv0 = *(const float4*)&xp[(size_t)j * 512];
      float4 xv1 = *(const float4*)&xp[(size_t)(j + 1) * 512];
      float2 p0 = *(const float2*)&pl[rr][j];
      float2 p1 = *(const float2*)&pl[rr + 4][j];
      a0.x = fmaf(p0.x, xv0.x, a0.x); a0.y = fmaf(p0.x, xv0.y, a0.y);
      a0.z = fmaf(p0.x, xv0.z, a0.z); a0.w = fmaf(p0.x, xv0.w, a0.w);
      a1.x = fmaf(p1.x, xv0.x, a1.x); a1.y = fmaf(p1.x, xv0.y, a1.y);
      a1.z = fmaf(p1.x, xv0.z, a1.z); a1.w = fmaf(p1.x, xv0.w, a1.w);
      a0.x = fmaf(p0.y, xv1.x, a0.x); a0.y = fmaf(p0.y, xv1.y, a0.y);
      a0.z = fmaf(p0.y, xv1.z, a0.z); a0.w = fmaf(p0.y, xv1.w, a0.w);
      a1.x = fmaf(p1.y, xv1.x, a1.x); a1.y = fmaf(p1.y, xv1.y, a1.y);
      a1.z = fmaf(p1.y, xv1.z, a1.z); a1.w = fmaf(p1.y, xv1.w, a1.w);
    }
    __syncthreads();  // all pl reads done before scratch overwrite
    float4* sc4 = (float4*)pl;
    sc4[(rr * 32 + fq) + 256 * jh] = a0;
    sc4[((rr + 4) * 32 + fq) + 256 * jh] = a1;
    __syncthreads();
    if (t < 256) {
      int r = t >> 5, ff = t & 31;
      float4 u0 = sc4[(r * 32 + ff)];
      float4 u1 = sc4[(r * 32 + ff) + 256];
      float4 u2 = sc4[(r * 32 + ff) + 512];
      float4 u3 = sc4[(r * 32 + ff) + 768];
      float s0 = idl[r];
      osum.x += (u0.x + u1.x + u2.x + u3.x) * s0;
      osum.y += (u0.y + u1.y + u2.y + u3.y) * s0;
      osum.z += (u0.z + u1.z + u2.z + u3.z) * s0;
      osum.w += (u0.w + u1.w + u2.w + u3.w) * s0;
    }
  }
  if (t < 256) {
    int r = t >> 5, ff = t & 31;
    float4 bb = *(const float4*)&bg[ff * 4];
    float4 o = {osum.x + bb.x, osum.y + bb.y, osum.z + bb.z, osum.w + bb.w};
    *(float4*)&xo[(size_t)(b * NN + i0 + r) * 128 + ff * 4] = o;
  }
}

// ------- kF: final_adj = sigmoid(x @ x^T) --------------------------------
__global__ void kF(const float* __restrict__ x, float* __restrict__ out) {
  int b = blockIdx.z, i0 = blockIdx.y * 32, j0 = blockIdx.x * 32;
  __shared__ alignas(16) float As[32][132];
  __shared__ alignas(16) float Bs[32][132];
  int t = threadIdx.x;  // 256
  for (int q = t; q < 1024; q += 256) {
    int r = q >> 5, c = (q & 31) * 4;
    *(float4*)&As[r][c] = *(const float4*)&x[(size_t)(b * NN + i0 + r) * 128 + c];
    *(float4*)&Bs[r][c] = *(const float4*)&x[(size_t)(b * NN + j0 + r) * 128 + c];
  }
  __syncthreads();
  int tx = t & 15, ty = t >> 4;
  int ia = 2 * ty, ib = ia + 1, ja = tx, jb = tx + 16;
  float a00 = 0, a01 = 0, a10 = 0, a11 = 0;
  for (int k = 0; k < 128; k += 4) {
    float4 A0 = *(float4*)&As[ia][k];
    float4 A1 = *(float4*)&As[ib][k];
    float4 B0 = *(float4*)&Bs[ja][k];
    float4 B1 = *(float4*)&Bs[jb][k];
#pragma unroll
    for (int kk = 0; kk < 4; ++kk) {
      float av = ((float*)&A0)[kk], av1 = ((float*)&A1)[kk];
      float bv = ((float*)&B0)[kk], bv1 = ((float*)&B1)[kk];
      a00 = fmaf(av, bv, a00);
      a01 = fmaf(av, bv1, a01);
      a10 = fmaf(av1, bv, a10);
      a11 = fmaf(av1, bv1, a11);
    }
  }
  size_t r0 = (size_t)(b * NN + i0 + ia) * NN + j0;
  size_t r1 = (size_t)(b * NN + i0 + ib) * NN + j0;
  out[r0 + ja] = 1.0f / (1.0f + __expf(-a00));
  out[r0 + jb] = 1.0f / (1.0f + __expf(-a01));
  out[r1 + ja] = 1.0f / (1.0f + __expf(-a10));
  out[r1 + jb] = 1.0f / (1.0f + __expf(-a11));
}

extern "C" void kernel_launch(void* const* d_in, const int* in_sizes, int n_in,
                              void* d_out, int out_size, void* d_ws, size_t ws_size,
                              hipStream_t stream) {
  (void)in_sizes; (void)n_in; (void)out_size; (void)ws_size;
  const float* X   = (const float*)d_in[0];
  const float* C   = (const float*)d_in[1];
  const float* W1  = (const float*)d_in[2];
  const float* b1  = (const float*)d_in[3];
  const float* W2  = (const float*)d_in[4];
  const float* b2  = (const float*)d_in[5];
  const float* Wg  = (const float*)d_in[6];
  const float* as_ = (const float*)d_in[7];
  const float* ad_ = (const float*)d_in[8];
  const float* bg  = (const float*)d_in[9];
  float* out = (float*)d_out;
  float* ws = (float*)d_ws;

  float* ha    = ws;                 // 262144
  float* hb    = ws + 262144;        // 262144
  float* Km    = ws + 524288;        // 1048576
  float* ru    = ws + 1572864;       // 2048
  unsigned* bar = (unsigned*)(ws + 1574912);  // 16 slots
  float* xw    = ws + 1591296;       // 1048576
  float* ssT   = ws + 2639872;       // 8192
  float* sdT   = ws + 2648064;       // 8192
  float* x1    = ws + 2656256;       // 262144
  float* x2    = ws + 2918400;       // 262144
  float* rvpA  = ws + 3180544;       // 32768 (16 slabs x 4 b x 512 j)
  float* rvpB  = ws + 3246080;       // 32768
  float* adj   = out + 1048576;

  kA<<<dim3(64, 4), 128, 0, stream>>>(X, W1, b1, ha, hb, ru, bar);
  kB<<<dim3(16, 16, 4), 256, 0, stream>>>(ha, hb, C, W1, W2, b2, Km, ru);
  // Sinkhorn: fully fused, manual device barrier (64 blocks, co-resident)
  kSink2<<<dim3(16, 4), 512, 0, stream>>>(Km, ru, rvpA, rvpB, adj, bar);
  // GAT layer 0
  kG1f<<<dim3(64, 4), 256, 0, stream>>>(X, Wg, as_, ad_, xw, ssT, sdT);
  kG2m<<<dim3(64, 4), 512, 0, stream>>>(xw, ssT, sdT, bg, x1);
  // GAT layer 1
  kG1f<<<dim3(64, 4), 256, 0, stream>>>(x1, Wg + 65536, as_ + 512, ad_ + 512, xw, ssT, sdT);
  kG2m<<<dim3(64, 4), 512, 0, stream>>>(xw, ssT, sdT, bg + 128, x2);
  // final adjacency
  kF<<<dim3(16, 16, 4), 256, 0, stream>>>(x2, out);
}

// Round 8
// 189.171 us; speedup vs baseline: 1.3175x; 1.3175x over previous
//
#include <hip/hip_runtime.h>
#include <math.h>

#define NB 4
#define NN 512

// ---------------- kA: ha = X@Wa + b1, hb = X@Wb ; zero ru ----------------
__global__ void kA(const float* __restrict__ X, const float* __restrict__ W1,
                   const float* __restrict__ b1, float* __restrict__ ha,
                   float* __restrict__ hb, float* __restrict__ ru) {
  int b = blockIdx.y, n0 = blockIdx.x * 8;
  __shared__ float xs[8][128];
  int t = threadIdx.x;  // 128 threads
  for (int q = t; q < 1024; q += 128) {
    int r = q >> 7, f = q & 127;
    xs[r][f] = X[(size_t)(b * NN + n0 + r) * 128 + f];
  }
  int flat = b * 64 + blockIdx.x;
  if (flat < 16) ru[flat * 128 + t] = 0.f;
  __syncthreads();
  float accA[8] = {0,0,0,0,0,0,0,0}, accB[8] = {0,0,0,0,0,0,0,0};
  for (int f = 0; f < 128; ++f) {
    float wa = W1[f * 128 + t];
    float wb = W1[(128 + f) * 128 + t];
#pragma unroll
    for (int r = 0; r < 8; ++r) {
      accA[r] = fmaf(xs[r][f], wa, accA[r]);
      accB[r] = fmaf(xs[r][f], wb, accB[r]);
    }
  }
  float b1v = b1[t];
#pragma unroll
  for (int r = 0; r < 8; ++r) {
    ha[(size_t)(b * NN + n0 + r) * 128 + t] = accA[r] + b1v;
    hb[(size_t)(b * NN + n0 + r) * 128 + t] = accB[r];
  }
}

// ------- kB: K = exp(-5*cost), cost = relu(ha_i+hb_j+dist*wd)@W2 + b2 ----
__global__ void kB(const float* __restrict__ ha, const float* __restrict__ hb,
                   const float* __restrict__ coords, const float* __restrict__ W1,
                   const float* __restrict__ W2, const float* __restrict__ b2,
                   float* __restrict__ Km, float* __restrict__ ru) {
  int b = blockIdx.z, i0 = blockIdx.y * 32, j0 = blockIdx.x * 32;
  __shared__ alignas(16) float As[32][132];
  __shared__ alignas(16) float Bs[32][132];
  __shared__ alignas(16) float wd[128];
  __shared__ alignas(16) float w2[128];
  __shared__ float ci[32][3], cj[32][3];
  int t = threadIdx.x;  // 256
  for (int q = t; q < 1024; q += 256) {
    int r = q >> 5, c = (q & 31) * 4;
    *(float4*)&As[r][c] = *(const float4*)&ha[(size_t)(b * NN + i0 + r) * 128 + c];
    *(float4*)&Bs[r][c] = *(const float4*)&hb[(size_t)(b * NN + j0 + r) * 128 + c];
  }
  if (t < 128) { wd[t] = W1[256 * 128 + t]; w2[t] = W2[t]; }
  if (t < 96) ((float*)ci)[t] = coords[(size_t)(b * NN + i0) * 3 + t];
  else if (t < 192) ((float*)cj)[t - 96] = coords[(size_t)(b * NN + j0) * 3 + (t - 96)];
  __syncthreads();
  int tx = t & 15, ty = t >> 4;
  int ia = 2 * ty, ib = ia + 1, ja = tx, jb = tx + 16;
  float d00, d01, d10, d11;
  {
    float ax = ci[ia][0], ay = ci[ia][1], az = ci[ia][2];
    float bx = ci[ib][0], by = ci[ib][1], bz = ci[ib][2];
    float cx0 = cj[ja][0], cy0 = cj[ja][1], cz0 = cj[ja][2];
    float cx1 = cj[jb][0], cy1 = cj[jb][1], cz1 = cj[jb][2];
    float dx, dy, dz;
    dx = ax - cx0; dy = ay - cy0; dz = az - cz0;
    d00 = sqrtf(fmaxf(dx * dx + dy * dy + dz * dz, 0.f));
    dx = ax - cx1; dy = ay - cy1; dz = az - cz1;
    d01 = sqrtf(fmaxf(dx * dx + dy * dy + dz * dz, 0.f));
    dx = bx - cx0; dy = by - cy0; dz = bz - cz0;
    d10 = sqrtf(fmaxf(dx * dx + dy * dy + dz * dz, 0.f));
    dx = bx - cx1; dy = by - cy1; dz = bz - cz1;
    d11 = sqrtf(fmaxf(dx * dx + dy * dy + dz * dz, 0.f));
  }
  float a00 = 0, a01 = 0, a10 = 0, a11 = 0;
  for (int k = 0; k < 128; k += 4) {
    float4 A0 = *(float4*)&As[ia][k];
    float4 A1 = *(float4*)&As[ib][k];
    float4 B0 = *(float4*)&Bs[ja][k];
    float4 B1 = *(float4*)&Bs[jb][k];
    float4 W = *(float4*)&wd[k];
    float4 V = *(float4*)&w2[k];
#pragma unroll
    for (int kk = 0; kk < 4; ++kk) {
      float av = ((float*)&A0)[kk], av1 = ((float*)&A1)[kk];
      float bv = ((float*)&B0)[kk], bv1 = ((float*)&B1)[kk];
      float wv = ((float*)&W)[kk], vv = ((float*)&V)[kk];
      float t00 = fmaxf(fmaf(d00, wv, av + bv), 0.f);
      float t01 = fmaxf(fmaf(d01, wv, av + bv1), 0.f);
      float t10 = fmaxf(fmaf(d10, wv, av1 + bv), 0.f);
      float t11 = fmaxf(fmaf(d11, wv, av1 + bv1), 0.f);
      a00 = fmaf(t00, vv, a00);
      a01 = fmaf(t01, vv, a01);
      a10 = fmaf(t10, vv, a10);
      a11 = fmaf(t11, vv, a11);
    }
  }
  float b2v = b2[0];
  float k00 = __expf(-5.0f * (a00 + b2v));
  float k01 = __expf(-5.0f * (a01 + b2v));
  float k10 = __expf(-5.0f * (a10 + b2v));
  float k11 = __expf(-5.0f * (a11 + b2v));
  size_t r0 = (size_t)(b * NN + i0 + ia) * NN + j0;
  size_t r1 = (size_t)(b * NN + i0 + ib) * NN + j0;
  Km[r0 + ja] = k00; Km[r0 + jb] = k01;
  Km[r1 + ja] = k10; Km[r1 + jb] = k11;
  float s0 = k00 + k01, s1 = k10 + k11;
#pragma unroll
  for (int off = 1; off < 16; off <<= 1) {
    s0 += __shfl_xor(s0, off);
    s1 += __shfl_xor(s1, off);
  }
  if (tx == 0) {
    atomicAdd(&ru[b * NN + i0 + ia], s0);
    atomicAdd(&ru[b * NN + i0 + ib], s1);
  }
}

// ------- kCcol: rvp[ic] = partial col sums of K * (1/ru); 32-row slabs ---
__global__ __launch_bounds__(512) void kCcol(const float* __restrict__ Km,
                                             const float* __restrict__ ru,
                                             float* __restrict__ rvp) {
  int ic = blockIdx.x, b = blockIdx.y;  // ic < 16
  __shared__ float uinv[32];
  int t = threadIdx.x;  // 512
  if (t < 32) uinv[t] = 1.0f / ru[b * NN + ic * 32 + t];
  __syncthreads();
  const float* Kp = Km + (size_t)(b * NN + ic * 32) * NN + t;
  float acc = 0.f;
#pragma unroll 8
  for (int ii = 0; ii < 32; ++ii) acc = fmaf(Kp[(size_t)ii * NN], uinv[ii], acc);
  rvp[ic * 2048 + b * NN + t] = acc;
}

// ------- kCrc: fused Sinkhorn iteration (row pass + col partials) --------
__global__ __launch_bounds__(512) void kCrc(const float* __restrict__ Km,
                                            const float* __restrict__ rvpOld,
                                            float* __restrict__ rvpNew,
                                            float* __restrict__ ru) {
  int ic = blockIdx.x, b = blockIdx.y;  // (16, 4)
  __shared__ float vinv[512];
  __shared__ float uinv[32];
  int t = threadIdx.x;  // 512
  {
    float s = 0.f;
#pragma unroll
    for (int q = 0; q < 16; ++q) s += rvpOld[q * 2048 + b * NN + t];
    vinv[t] = 1.0f / s;
  }
  __syncthreads();
  int w = t >> 6, l = t & 63;  // 8 waves, 4 rows each
#pragma unroll
  for (int m = 0; m < 4; ++m) {
    int r = ic * 32 + w * 4 + m;
    const float* Kp = Km + (size_t)(b * NN + r) * NN;
    float acc = 0.f;
#pragma unroll
    for (int mm = 0; mm < 8; ++mm) acc = fmaf(Kp[l + 64 * mm], vinv[l + 64 * mm], acc);
#pragma unroll
    for (int off = 1; off < 64; off <<= 1) acc += __shfl_xor(acc, off);
    if (l == 0) { uinv[w * 4 + m] = 1.0f / acc; ru[b * NN + r] = acc; }
  }
  __syncthreads();
  {
    const float* Kp = Km + (size_t)(b * NN + ic * 32) * NN + t;
    float acc = 0.f;
#pragma unroll 8
    for (int ii = 0; ii < 32; ++ii) acc = fmaf(Kp[(size_t)ii * NN], uinv[ii], acc);
    rvpNew[ic * 2048 + b * NN + t] = acc;
  }
}

// ------- kAdj: adj = (1/ru_i) * K * (1/rv_j) -----------------------------
__global__ __launch_bounds__(512) void kAdj(const float* __restrict__ Km,
                                            const float* __restrict__ ru,
                                            const float* __restrict__ rvp,
                                            float* __restrict__ out) {
  int rc = blockIdx.x, b = blockIdx.y;  // (16, 4)
  __shared__ float vinv[512];
  __shared__ float uinv[32];
  int t = threadIdx.x;  // 512
  {
    float s = 0.f;
#pragma unroll
    for (int ic = 0; ic < 16; ++ic) s += rvp[ic * 2048 + b * NN + t];
    vinv[t] = 1.0f / s;
  }
  if (t < 32) uinv[t] = 1.0f / ru[b * NN + rc * 32 + t];
  __syncthreads();
  float vj = vinv[t];
  const float* Kp = Km + (size_t)(b * NN + rc * 32) * NN + t;
  float* op = out + (size_t)(b * NN + rc * 32) * NN + t;
#pragma unroll 4
  for (int m = 0; m < 32; ++m) {
    op[(size_t)m * NN] = Kp[(size_t)m * NN] * uinv[m] * vj;
  }
}

// ------- kG1f: xw = x @ Wg[l] + fused s_src/s_dst epilogue ---------------
__global__ void kG1f(const float* __restrict__ x, const float* __restrict__ Wg,
                     const float* __restrict__ asrc, const float* __restrict__ adst,
                     float* __restrict__ xw, float* __restrict__ ssT,
                     float* __restrict__ sdT) {
  int b = blockIdx.y, n0 = blockIdx.x * 8;
  __shared__ float xs[8][128];
  __shared__ float red[4][8][4];  // wave, r, {s_c0, d_c0, s_c1, d_c1}
  int t = threadIdx.x;  // 256
  for (int q = t; q < 1024; q += 256) {
    int r = q >> 7, f = q & 127;
    xs[r][f] = x[(size_t)(b * NN + n0 + r) * 128 + f];
  }
  __syncthreads();
  int c0 = t, c1 = t + 256;
  float acc0[8] = {0,0,0,0,0,0,0,0}, acc1[8] = {0,0,0,0,0,0,0,0};
  for (int f = 0; f < 128; ++f) {
    float w0 = Wg[f * 512 + c0], w1 = Wg[f * 512 + c1];
#pragma unroll
    for (int r = 0; r < 8; ++r) {
      float xv = xs[r][f];
      acc0[r] = fmaf(xv, w0, acc0[r]);
      acc1[r] = fmaf(xv, w1, acc1[r]);
    }
  }
#pragma unroll
  for (int r = 0; r < 8; ++r) {
    xw[(size_t)(b * NN + n0 + r) * 512 + c0] = acc0[r];
    xw[(size_t)(b * NN + n0 + r) * 512 + c1] = acc1[r];
  }
  float as0 = asrc[c0], ad0 = adst[c0];
  float as1 = asrc[c1], ad1 = adst[c1];
  int w = t >> 6, l = t & 63;
#pragma unroll
  for (int r = 0; r < 8; ++r) {
    float ps0 = acc0[r] * as0, pd0 = acc0[r] * ad0;
    float ps1 = acc1[r] * as1, pd1 = acc1[r] * ad1;
#pragma unroll
    for (int off = 1; off < 64; off <<= 1) {
      ps0 += __shfl_xor(ps0, off);
      pd0 += __shfl_xor(pd0, off);
      ps1 += __shfl_xor(ps1, off);
      pd1 += __shfl_xor(pd1, off);
    }
    if (l == 0) {
      red[w][r][0] = ps0; red[w][r][1] = pd0;
      red[w][r][2] = ps1; red[w][r][3] = pd1;
    }
  }
  __syncthreads();
  if (t < 64) {
    int r = t & 7, h = (t >> 3) & 3, sd = t >> 5;
    int wbase = (h & 1) ? 2 : 0;
    int which = (h < 2 ? 0 : 2) + sd;
    float s = red[wbase][r][which] + red[wbase + 1][r][which];
    float* dst = sd ? sdT : ssT;
    dst[(size_t)(b * 4 + h) * 512 + n0 + r] = s;
  }
}

// ------- kG2v: per (b, 8-row tile): 4 heads accumulated in registers -----
// thread map phase B: fq = t&31 (f quad), jh = t>>5 (16 j-chunks of 32)
// each thread owns all 8 rows -> 8 float4 accumulators, summed across heads
#define PLDV 520
__global__ __launch_bounds__(512) void kG2v(const float* __restrict__ xw,
                                            const float* __restrict__ ssT,
                                            const float* __restrict__ sdT,
                                            const float* __restrict__ bg,
                                            float* __restrict__ xo) {
  int b = blockIdx.y, i0 = blockIdx.x * 8;
  __shared__ alignas(16) float smem[8192];  // 32KB: pl[8][520] / sc4[8][8][32]
  __shared__ float ssb[512];
  __shared__ float sdl[4][8];
  __shared__ float smaxsh[8];
  __shared__ float mxl[8];
  int t = threadIdx.x;  // 512
  if (t < 32) {
    int h = t >> 3, r = t & 7;
    sdl[h][r] = sdT[(size_t)(b * 4 + h) * 512 + i0 + r];
  }
  int fq = t & 31, jh = t >> 5;       // phase B
  int il = t >> 6, jq = t & 63;       // phase A (wave il owns row il)
  float4 acc[8];
#pragma unroll
  for (int r = 0; r < 8; ++r) acc[r] = make_float4(0.f, 0.f, 0.f, 0.f);
  for (int h = 0; h < 4; ++h) {
    __syncthreads();  // prev phase-B pl reads done; sdl ready (h=0)
    {
      float v = ssT[(size_t)(b * 4 + h) * 512 + t];
      ssb[t] = v;
#pragma unroll
      for (int off = 1; off < 64; off <<= 1) v = fmaxf(v, __shfl_xor(v, off));
      if ((t & 63) == 0) smaxsh[t >> 6] = v;
    }
    __syncthreads();
    if (t < 8) {
      float m = smaxsh[0];
#pragma unroll
      for (int q = 1; q < 8; ++q) m = fmaxf(m, smaxsh[q]);
      float mm = sdl[h][t] + m;
      mxl[t] = (mm >= 0.f) ? mm : 0.2f * mm;
    }
    __syncthreads();
    // phase A: wave il computes row il's P, scale folded in
    {
      float mx = mxl[il], sdv = sdl[h][il];
      float pe[8];
      float den = 0.f;
#pragma unroll
      for (int jj = 0; jj < 8; ++jj) {
        int j = jj * 64 + jq;
        float e = sdv + ssb[j];
        e = (e >= 0.f) ? e : 0.2f * e;
        pe[jj] = __expf(e - mx);
        den += pe[jj];
      }
#pragma unroll
      for (int off = 1; off < 64; off <<= 1) den += __shfl_xor(den, off);
      float inv = 1.0f / (4.0f * den);
#pragma unroll
      for (int jj = 0; jj < 8; ++jj) smem[il * PLDV + jj * 64 + jq] = pe[jj] * inv;
    }
    __syncthreads();
    // phase B: 32 j per thread, 8 rows, accumulate across heads
    const float* xp = xw + (size_t)(b * NN) * 512 + h * 128 + fq * 4;
    int jbase = jh * 32;
#pragma unroll 4
    for (int jj = 0; jj < 32; ++jj) {
      int j = jbase + jj;
      float4 xv = *(const float4*)&xp[(size_t)j * 512];
#pragma unroll
      for (int r = 0; r < 8; ++r) {
        float p = smem[r * PLDV + j];
        acc[r].x = fmaf(p, xv.x, acc[r].x);
        acc[r].y = fmaf(p, xv.y, acc[r].y);
        acc[r].z = fmaf(p, xv.z, acc[r].z);
        acc[r].w = fmaf(p, xv.w, acc[r].w);
      }
    }
  }
  __syncthreads();  // all pl reads done before sc4 overwrite
  // wave-level jh-pair reduce (lanes 0-31 jh=2w, lanes 32-63 jh=2w+1)
  int w = t >> 6;
#pragma unroll
  for (int r = 0; r < 8; ++r) {
    acc[r].x += __shfl_xor(acc[r].x, 32);
    acc[r].y += __shfl_xor(acc[r].y, 32);
    acc[r].z += __shfl_xor(acc[r].z, 32);
    acc[r].w += __shfl_xor(acc[r].w, 32);
  }
  float4* sc4 = (float4*)smem;  // [w][r][fq]
  if ((t & 63) < 32) {
#pragma unroll
    for (int r = 0; r < 8; ++r) sc4[w * 256 + r * 32 + fq] = acc[r];
  }
  __syncthreads();
  if (t < 256) {
    int r = t >> 5, ff = t & 31;
    float4 bb = *(const float4*)&bg[ff * 4];
    float4 s = bb;
#pragma unroll
    for (int q = 0; q < 8; ++q) {
      float4 u = sc4[q * 256 + r * 32 + ff];
      s.x += u.x; s.y += u.y; s.z += u.z; s.w += u.w;
    }
    *(float4*)&xo[(size_t)(b * NN + i0 + r) * 128 + ff * 4] = s;
  }
}

// ------- kF: final_adj = sigmoid(x @ x^T) --------------------------------
__global__ void kF(const float* __restrict__ x, float* __restrict__ out) {
  int b = blockIdx.z, i0 = blockIdx.y * 32, j0 = blockIdx.x * 32;
  __shared__ alignas(16) float As[32][132];
  __shared__ alignas(16) float Bs[32][132];
  int t = threadIdx.x;  // 256
  for (int q = t; q < 1024; q += 256) {
    int r = q >> 5, c = (q & 31) * 4;
    *(float4*)&As[r][c] = *(const float4*)&x[(size_t)(b * NN + i0 + r) * 128 + c];
    *(float4*)&Bs[r][c] = *(const float4*)&x[(size_t)(b * NN + j0 + r) * 128 + c];
  }
  __syncthreads();
  int tx = t & 15, ty = t >> 4;
  int ia = 2 * ty, ib = ia + 1, ja = tx, jb = tx + 16;
  float a00 = 0, a01 = 0, a10 = 0, a11 = 0;
  for (int k = 0; k < 128; k += 4) {
    float4 A0 = *(float4*)&As[ia][k];
    float4 A1 = *(float4*)&As[ib][k];
    float4 B0 = *(float4*)&Bs[ja][k];
    float4 B1 = *(float4*)&Bs[jb][k];
#pragma unroll
    for (int kk = 0; kk < 4; ++kk) {
      float av = ((float*)&A0)[kk], av1 = ((float*)&A1)[kk];
      float bv = ((float*)&B0)[kk], bv1 = ((float*)&B1)[kk];
      a00 = fmaf(av, bv, a00);
      a01 = fmaf(av, bv1, a01);
      a10 = fmaf(av1, bv, a10);
      a11 = fmaf(av1, bv1, a11);
    }
  }
  size_t r0 = (size_t)(b * NN + i0 + ia) * NN + j0;
  size_t r1 = (size_t)(b * NN + i0 + ib) * NN + j0;
  out[r0 + ja] = 1.0f / (1.0f + __expf(-a00));
  out[r0 + jb] = 1.0f / (1.0f + __expf(-a01));
  out[r1 + ja] = 1.0f / (1.0f + __expf(-a10));
  out[r1 + jb] = 1.0f / (1.0f + __expf(-a11));
}

extern "C" void kernel_launch(void* const* d_in, const int* in_sizes, int n_in,
                              void* d_out, int out_size, void* d_ws, size_t ws_size,
                              hipStream_t stream) {
  (void)in_sizes; (void)n_in; (void)out_size; (void)ws_size;
  const float* X   = (const float*)d_in[0];
  const float* C   = (const float*)d_in[1];
  const float* W1  = (const float*)d_in[2];
  const float* b1  = (const float*)d_in[3];
  const float* W2  = (const float*)d_in[4];
  const float* b2  = (const float*)d_in[5];
  const float* Wg  = (const float*)d_in[6];
  const float* as_ = (const float*)d_in[7];
  const float* ad_ = (const float*)d_in[8];
  const float* bg  = (const float*)d_in[9];
  float* out = (float*)d_out;
  float* ws = (float*)d_ws;

  float* ha    = ws;                 // 262144
  float* hb    = ws + 262144;        // 262144
  float* Km    = ws + 524288;        // 1048576
  float* ru    = ws + 1572864;       // 2048
  float* xw    = ws + 1591296;       // 1048576
  float* ssT   = ws + 2639872;       // 8192
  float* sdT   = ws + 2648064;       // 8192
  float* x1    = ws + 2656256;       // 262144
  float* x2    = ws + 2918400;       // 262144
  float* rvpA  = ws + 3180544;       // 32768 (16 slabs x 4 b x 512 j)
  float* rvpB  = ws + 3246080;       // 32768
  float* adj   = out + 1048576;

  kA<<<dim3(64, 4), 128, 0, stream>>>(X, W1, b1, ha, hb, ru);
  kB<<<dim3(16, 16, 4), 256, 0, stream>>>(ha, hb, C, W1, W2, b2, Km, ru);
  // Sinkhorn: launch chain (measured faster than any intra-kernel sync)
  kCcol<<<dim3(16, 4), 512, 0, stream>>>(Km, ru, rvpA);
  for (int it = 0; it < 9; ++it) {
    const float* src = (it & 1) ? rvpB : rvpA;
    float* dst = (it & 1) ? rvpA : rvpB;
    kCrc<<<dim3(16, 4), 512, 0, stream>>>(Km, src, dst, ru);
  }
  kAdj<<<dim3(16, 4), 512, 0, stream>>>(Km, ru, rvpB, adj);
  // GAT layer 0
  kG1f<<<dim3(64, 4), 256, 0, stream>>>(X, Wg, as_, ad_, xw, ssT, sdT);
  kG2v<<<dim3(64, 4), 512, 0, stream>>>(xw, ssT, sdT, bg, x1);
  // GAT layer 1
  kG1f<<<dim3(64, 4), 256, 0, stream>>>(x1, Wg + 65536, as_ + 512, ad_ + 512, xw, ssT, sdT);
  kG2v<<<dim3(64, 4), 512, 0, stream>>>(xw, ssT, sdT, bg + 128, x2);
  // final adjacency
  kF<<<dim3(16, 16, 4), 256, 0, stream>>>(x2, out);
}

// Round 9
// 177.793 us; speedup vs baseline: 1.4018x; 1.0640x over previous
//
#include <hip/hip_runtime.h>
#include <math.h>

#define NB 4
#define NN 512

// ---------------- kA: ha = X@Wa + b1, hb = X@Wb ; zero ru ----------------
__global__ void kA(const float* __restrict__ X, const float* __restrict__ W1,
                   const float* __restrict__ b1, float* __restrict__ ha,
                   float* __restrict__ hb, float* __restrict__ ru) {
  int b = blockIdx.y, n0 = blockIdx.x * 8;
  __shared__ float xs[8][128];
  int t = threadIdx.x;  // 128 threads
  for (int q = t; q < 1024; q += 128) {
    int r = q >> 7, f = q & 127;
    xs[r][f] = X[(size_t)(b * NN + n0 + r) * 128 + f];
  }
  int flat = b * 64 + blockIdx.x;
  if (flat < 16) ru[flat * 128 + t] = 0.f;
  __syncthreads();
  float accA[8] = {0,0,0,0,0,0,0,0}, accB[8] = {0,0,0,0,0,0,0,0};
  for (int f = 0; f < 128; ++f) {
    float wa = W1[f * 128 + t];
    float wb = W1[(128 + f) * 128 + t];
#pragma unroll
    for (int r = 0; r < 8; ++r) {
      accA[r] = fmaf(xs[r][f], wa, accA[r]);
      accB[r] = fmaf(xs[r][f], wb, accB[r]);
    }
  }
  float b1v = b1[t];
#pragma unroll
  for (int r = 0; r < 8; ++r) {
    ha[(size_t)(b * NN + n0 + r) * 128 + t] = accA[r] + b1v;
    hb[(size_t)(b * NN + n0 + r) * 128 + t] = accB[r];
  }
}

// ------- kB: K = exp(-5*cost), cost = relu(ha_i+hb_j+dist*wd)@W2 + b2 ----
__global__ void kB(const float* __restrict__ ha, const float* __restrict__ hb,
                   const float* __restrict__ coords, const float* __restrict__ W1,
                   const float* __restrict__ W2, const float* __restrict__ b2,
                   float* __restrict__ Km, float* __restrict__ ru) {
  int b = blockIdx.z, i0 = blockIdx.y * 32, j0 = blockIdx.x * 32;
  __shared__ alignas(16) float As[32][132];
  __shared__ alignas(16) float Bs[32][132];
  __shared__ alignas(16) float wd[128];
  __shared__ alignas(16) float w2[128];
  __shared__ float ci[32][3], cj[32][3];
  int t = threadIdx.x;  // 256
  for (int q = t; q < 1024; q += 256) {
    int r = q >> 5, c = (q & 31) * 4;
    *(float4*)&As[r][c] = *(const float4*)&ha[(size_t)(b * NN + i0 + r) * 128 + c];
    *(float4*)&Bs[r][c] = *(const float4*)&hb[(size_t)(b * NN + j0 + r) * 128 + c];
  }
  if (t < 128) { wd[t] = W1[256 * 128 + t]; w2[t] = W2[t]; }
  if (t < 96) ((float*)ci)[t] = coords[(size_t)(b * NN + i0) * 3 + t];
  else if (t < 192) ((float*)cj)[t - 96] = coords[(size_t)(b * NN + j0) * 3 + (t - 96)];
  __syncthreads();
  int tx = t & 15, ty = t >> 4;
  int ia = 2 * ty, ib = ia + 1, ja = tx, jb = tx + 16;
  float d00, d01, d10, d11;
  {
    float ax = ci[ia][0], ay = ci[ia][1], az = ci[ia][2];
    float bx = ci[ib][0], by = ci[ib][1], bz = ci[ib][2];
    float cx0 = cj[ja][0], cy0 = cj[ja][1], cz0 = cj[ja][2];
    float cx1 = cj[jb][0], cy1 = cj[jb][1], cz1 = cj[jb][2];
    float dx, dy, dz;
    dx = ax - cx0; dy = ay - cy0; dz = az - cz0;
    d00 = sqrtf(fmaxf(dx * dx + dy * dy + dz * dz, 0.f));
    dx = ax - cx1; dy = ay - cy1; dz = az - cz1;
    d01 = sqrtf(fmaxf(dx * dx + dy * dy + dz * dz, 0.f));
    dx = bx - cx0; dy = by - cy0; dz = bz - cz0;
    d10 = sqrtf(fmaxf(dx * dx + dy * dy + dz * dz, 0.f));
    dx = bx - cx1; dy = by - cy1; dz = bz - cz1;
    d11 = sqrtf(fmaxf(dx * dx + dy * dy + dz * dz, 0.f));
  }
  float a00 = 0, a01 = 0, a10 = 0, a11 = 0;
  for (int k = 0; k < 128; k += 4) {
    float4 A0 = *(float4*)&As[ia][k];
    float4 A1 = *(float4*)&As[ib][k];
    float4 B0 = *(float4*)&Bs[ja][k];
    float4 B1 = *(float4*)&Bs[jb][k];
    float4 W = *(float4*)&wd[k];
    float4 V = *(float4*)&w2[k];
#pragma unroll
    for (int kk = 0; kk < 4; ++kk) {
      float av = ((float*)&A0)[kk], av1 = ((float*)&A1)[kk];
      float bv = ((float*)&B0)[kk], bv1 = ((float*)&B1)[kk];
      float wv = ((float*)&W)[kk], vv = ((float*)&V)[kk];
      float t00 = fmaxf(fmaf(d00, wv, av + bv), 0.f);
      float t01 = fmaxf(fmaf(d01, wv, av + bv1), 0.f);
      float t10 = fmaxf(fmaf(d10, wv, av1 + bv), 0.f);
      float t11 = fmaxf(fmaf(d11, wv, av1 + bv1), 0.f);
      a00 = fmaf(t00, vv, a00);
      a01 = fmaf(t01, vv, a01);
      a10 = fmaf(t10, vv, a10);
      a11 = fmaf(t11, vv, a11);
    }
  }
  float b2v = b2[0];
  float k00 = __expf(-5.0f * (a00 + b2v));
  float k01 = __expf(-5.0f * (a01 + b2v));
  float k10 = __expf(-5.0f * (a10 + b2v));
  float k11 = __expf(-5.0f * (a11 + b2v));
  size_t r0 = (size_t)(b * NN + i0 + ia) * NN + j0;
  size_t r1 = (size_t)(b * NN + i0 + ib) * NN + j0;
  Km[r0 + ja] = k00; Km[r0 + jb] = k01;
  Km[r1 + ja] = k10; Km[r1 + jb] = k11;
  float s0 = k00 + k01, s1 = k10 + k11;
#pragma unroll
  for (int off = 1; off < 16; off <<= 1) {
    s0 += __shfl_xor(s0, off);
    s1 += __shfl_xor(s1, off);
  }
  if (tx == 0) {
    atomicAdd(&ru[b * NN + i0 + ia], s0);
    atomicAdd(&ru[b * NN + i0 + ib], s1);
  }
}

// ================= device roles (512 threads each) =======================

// Sinkhorn first col-partials: rvp[ic] = partial col sums of K * (1/ru)
__device__ __forceinline__ void dCcol(const float* __restrict__ Km,
                                      const float* __restrict__ ru,
                                      float* __restrict__ rvp,
                                      float* sm, int ic, int b) {
  float* uinv = sm;  // 32
  int t = threadIdx.x;
  if (t < 32) uinv[t] = 1.0f / ru[b * NN + ic * 32 + t];
  __syncthreads();
  const float* Kp = Km + (size_t)(b * NN + ic * 32) * NN + t;
  float acc = 0.f;
#pragma unroll 8
  for (int ii = 0; ii < 32; ++ii) acc = fmaf(Kp[(size_t)ii * NN], uinv[ii], acc);
  rvp[ic * 2048 + b * NN + t] = acc;
}

// Sinkhorn iteration: row pass + new col partials
__device__ __forceinline__ void dCrc(const float* __restrict__ Km,
                                     const float* __restrict__ rvpOld,
                                     float* __restrict__ rvpNew,
                                     float* __restrict__ ru,
                                     float* sm, int ic, int b) {
  float* vinv = sm;        // 512
  float* uinv = sm + 512;  // 32
  int t = threadIdx.x;
  {
    float s = 0.f;
#pragma unroll
    for (int q = 0; q < 16; ++q) s += rvpOld[q * 2048 + b * NN + t];
    vinv[t] = 1.0f / s;
  }
  __syncthreads();
  int w = t >> 6, l = t & 63;
#pragma unroll
  for (int m = 0; m < 4; ++m) {
    int r = ic * 32 + w * 4 + m;
    const float* Kp = Km + (size_t)(b * NN + r) * NN;
    float acc = 0.f;
#pragma unroll
    for (int mm = 0; mm < 8; ++mm) acc = fmaf(Kp[l + 64 * mm], vinv[l + 64 * mm], acc);
#pragma unroll
    for (int off = 1; off < 64; off <<= 1) acc += __shfl_xor(acc, off);
    if (l == 0) { uinv[w * 4 + m] = 1.0f / acc; ru[b * NN + r] = acc; }
  }
  __syncthreads();
  {
    const float* Kp = Km + (size_t)(b * NN + ic * 32) * NN + t;
    float acc = 0.f;
#pragma unroll 8
    for (int ii = 0; ii < 32; ++ii) acc = fmaf(Kp[(size_t)ii * NN], uinv[ii], acc);
    rvpNew[ic * 2048 + b * NN + t] = acc;
  }
}

// GAT GEMM + logit projections, 512 thr: 1 col/thread, 8 rows
__device__ __forceinline__ void dG1f(const float* __restrict__ x,
                                     const float* __restrict__ Wg,
                                     const float* __restrict__ asrc,
                                     const float* __restrict__ adst,
                                     float* __restrict__ xw,
                                     float* __restrict__ ssT,
                                     float* __restrict__ sdT,
                                     float* sm, int bx, int b) {
  int n0 = bx * 8;
  float* xs = sm;          // 1024: [8][128]
  float* red = sm + 1024;  // 128: [8 waves][8 r][2]
  int t = threadIdx.x;  // 512
  for (int q = t; q < 1024; q += 512)
    xs[q] = x[(size_t)(b * NN + n0 + (q >> 7)) * 128 + (q & 127)];
  __syncthreads();
  int c = t;
  float acc[8] = {0,0,0,0,0,0,0,0};
  for (int f = 0; f < 128; ++f) {
    float w0 = Wg[f * 512 + c];
#pragma unroll
    for (int r = 0; r < 8; ++r) acc[r] = fmaf(xs[r * 128 + f], w0, acc[r]);
  }
#pragma unroll
  for (int r = 0; r < 8; ++r)
    xw[(size_t)(b * NN + n0 + r) * 512 + c] = acc[r];
  float asv = asrc[c], adv = adst[c];
  int w = t >> 6, l = t & 63;
#pragma unroll
  for (int r = 0; r < 8; ++r) {
    float ps = acc[r] * asv, pd = acc[r] * adv;
#pragma unroll
    for (int off = 1; off < 64; off <<= 1) {
      ps += __shfl_xor(ps, off);
      pd += __shfl_xor(pd, off);
    }
    if (l == 0) { red[w * 16 + r * 2] = ps; red[w * 16 + r * 2 + 1] = pd; }
  }
  __syncthreads();
  if (t < 64) {
    int h = t >> 4, rr = t & 7, sd = (t >> 3) & 1;
    float s = red[(2 * h) * 16 + rr * 2 + sd] + red[(2 * h + 1) * 16 + rr * 2 + sd];
    float* dst = sd ? sdT : ssT;
    dst[(size_t)(b * 4 + h) * 512 + n0 + rr] = s;
  }
}

// GAT softmax+PV, 4 heads accumulated, 512 thr (proven kG2v body)
#define PLDV 520
__device__ __forceinline__ void dG2v(const float* __restrict__ xw,
                                     const float* __restrict__ ssT,
                                     const float* __restrict__ sdT,
                                     const float* __restrict__ bg,
                                     float* __restrict__ xo,
                                     float* sm, int bx, int b) {
  int i0 = bx * 8;
  float* pls = sm;             // 8192
  float* ssb = sm + 8192;      // 512
  float* sdl = sm + 8704;      // 32 [h*8+r]
  float* smaxsh = sm + 8736;   // 8
  float* mxl = sm + 8744;      // 8
  int t = threadIdx.x;  // 512
  if (t < 32) {
    int h = t >> 3, r = t & 7;
    sdl[h * 8 + r] = sdT[(size_t)(b * 4 + h) * 512 + i0 + r];
  }
  int fq = t & 31, jh = t >> 5;
  int il = t >> 6, jq = t & 63;
  float4 acc[8];
#pragma unroll
  for (int r = 0; r < 8; ++r) acc[r] = make_float4(0.f, 0.f, 0.f, 0.f);
  for (int h = 0; h < 4; ++h) {
    __syncthreads();
    {
      float v = ssT[(size_t)(b * 4 + h) * 512 + t];
      ssb[t] = v;
#pragma unroll
      for (int off = 1; off < 64; off <<= 1) v = fmaxf(v, __shfl_xor(v, off));
      if ((t & 63) == 0) smaxsh[t >> 6] = v;
    }
    __syncthreads();
    if (t < 8) {
      float m = smaxsh[0];
#pragma unroll
      for (int q = 1; q < 8; ++q) m = fmaxf(m, smaxsh[q]);
      float mm = sdl[h * 8 + t] + m;
      mxl[t] = (mm >= 0.f) ? mm : 0.2f * mm;
    }
    __syncthreads();
    {
      float mx = mxl[il], sdv = sdl[h * 8 + il];
      float pe[8];
      float den = 0.f;
#pragma unroll
      for (int jj = 0; jj < 8; ++jj) {
        int j = jj * 64 + jq;
        float e = sdv + ssb[j];
        e = (e >= 0.f) ? e : 0.2f * e;
        pe[jj] = __expf(e - mx);
        den += pe[jj];
      }
#pragma unroll
      for (int off = 1; off < 64; off <<= 1) den += __shfl_xor(den, off);
      float inv = 1.0f / (4.0f * den);
#pragma unroll
      for (int jj = 0; jj < 8; ++jj) pls[il * PLDV + jj * 64 + jq] = pe[jj] * inv;
    }
    __syncthreads();
    const float* xp = xw + (size_t)(b * NN) * 512 + h * 128 + fq * 4;
    int jbase = jh * 32;
#pragma unroll 4
    for (int jj = 0; jj < 32; ++jj) {
      int j = jbase + jj;
      float4 xv = *(const float4*)&xp[(size_t)j * 512];
#pragma unroll
      for (int r = 0; r < 8; ++r) {
        float p = pls[r * PLDV + j];
        acc[r].x = fmaf(p, xv.x, acc[r].x);
        acc[r].y = fmaf(p, xv.y, acc[r].y);
        acc[r].z = fmaf(p, xv.z, acc[r].z);
        acc[r].w = fmaf(p, xv.w, acc[r].w);
      }
    }
  }
  __syncthreads();
  int w = t >> 6;
#pragma unroll
  for (int r = 0; r < 8; ++r) {
    acc[r].x += __shfl_xor(acc[r].x, 32);
    acc[r].y += __shfl_xor(acc[r].y, 32);
    acc[r].z += __shfl_xor(acc[r].z, 32);
    acc[r].w += __shfl_xor(acc[r].w, 32);
  }
  float4* sc4 = (float4*)pls;
  if ((t & 63) < 32) {
#pragma unroll
    for (int r = 0; r < 8; ++r) sc4[w * 256 + r * 32 + fq] = acc[r];
  }
  __syncthreads();
  if (t < 256) {
    int r = t >> 5, ff = t & 31;
    float4 bb = *(const float4*)&bg[ff * 4];
    float4 s = bb;
#pragma unroll
    for (int q = 0; q < 8; ++q) {
      float4 u = sc4[q * 256 + r * 32 + ff];
      s.x += u.x; s.y += u.y; s.z += u.z; s.w += u.w;
    }
    *(float4*)&xo[(size_t)(b * NN + i0 + r) * 128 + ff * 4] = s;
  }
}

// final_adj tile, 512 thr: 32x32, 2 outputs/thread
__device__ __forceinline__ void dF(const float* __restrict__ x,
                                   float* __restrict__ out,
                                   float* sm, int fid, int b) {
  int i0 = (fid >> 4) * 32, j0 = (fid & 15) * 32;
  float* As = sm;          // [32][132]
  float* Bs = sm + 4224;   // [32][132]
  int t = threadIdx.x;  // 512
  for (int q = t; q < 1024; q += 512) {
    int r = q >> 5, c = (q & 31) * 4;
    *(float4*)&As[r * 132 + c] = *(const float4*)&x[(size_t)(b * NN + i0 + r) * 128 + c];
    *(float4*)&Bs[r * 132 + c] = *(const float4*)&x[(size_t)(b * NN + j0 + r) * 128 + c];
  }
  __syncthreads();
  int tx = t & 31, ty = t >> 5;
  int ia = 2 * ty, ib = ia + 1;
  float a0 = 0.f, a1 = 0.f;
  for (int k = 0; k < 128; k += 4) {
    float4 A0 = *(float4*)&As[ia * 132 + k];
    float4 A1 = *(float4*)&As[ib * 132 + k];
    float4 B0 = *(float4*)&Bs[tx * 132 + k];
#pragma unroll
    for (int kk = 0; kk < 4; ++kk) {
      a0 = fmaf(((float*)&A0)[kk], ((float*)&B0)[kk], a0);
      a1 = fmaf(((float*)&A1)[kk], ((float*)&B0)[kk], a1);
    }
  }
  out[(size_t)(b * NN + i0 + ia) * NN + j0 + tx] = 1.0f / (1.0f + __expf(-a0));
  out[(size_t)(b * NN + i0 + ib) * NN + j0 + tx] = 1.0f / (1.0f + __expf(-a1));
}

// ================= combined node kernels ================================

__global__ __launch_bounds__(512) void nCcolG1f(
    const float* Km, const float* ru, float* rvpA,
    const float* X, const float* Wg, const float* as_, const float* ad_,
    float* xw, float* ssT, float* sdT) {
  __shared__ alignas(16) float sm[1280];
  if (blockIdx.x < 16) dCcol(Km, ru, rvpA, sm, blockIdx.x, blockIdx.y);
  else dG1f(X, Wg, as_, ad_, xw, ssT, sdT, sm, blockIdx.x - 16, blockIdx.y);
}

__global__ __launch_bounds__(512) void nCrcG2v(
    const float* Km, const float* rvpOld, float* rvpNew, float* ru,
    const float* xw, const float* ssT, const float* sdT,
    const float* bg, float* xo) {
  __shared__ alignas(16) float sm[8752];
  if (blockIdx.x < 16) dCrc(Km, rvpOld, rvpNew, ru, sm, blockIdx.x, blockIdx.y);
  else dG2v(xw, ssT, sdT, bg, xo, sm, blockIdx.x - 16, blockIdx.y);
}

__global__ __launch_bounds__(512) void nCrcG1f(
    const float* Km, const float* rvpOld, float* rvpNew, float* ru,
    const float* x, const float* Wg, const float* as_, const float* ad_,
    float* xw, float* ssT, float* sdT) {
  __shared__ alignas(16) float sm[1280];
  if (blockIdx.x < 16) dCrc(Km, rvpOld, rvpNew, ru, sm, blockIdx.x, blockIdx.y);
  else dG1f(x, Wg, as_, ad_, xw, ssT, sdT, sm, blockIdx.x - 16, blockIdx.y);
}

__global__ __launch_bounds__(512) void nCrcF(
    const float* Km, const float* rvpOld, float* rvpNew, float* ru,
    const float* x, float* outF) {
  __shared__ alignas(16) float sm[8448];
  if (blockIdx.x < 16) dCrc(Km, rvpOld, rvpNew, ru, sm, blockIdx.x, blockIdx.y);
  else dF(x, outF, sm, blockIdx.x - 16, blockIdx.y);
}

__global__ __launch_bounds__(512) void kCrc(
    const float* Km, const float* rvpOld, float* rvpNew, float* ru) {
  __shared__ alignas(16) float sm[544];
  dCrc(Km, rvpOld, rvpNew, ru, sm, blockIdx.x, blockIdx.y);
}

// ------- kAdj: adj = (1/ru_i) * K * (1/rv_j) -----------------------------
__global__ __launch_bounds__(512) void kAdj(const float* __restrict__ Km,
                                            const float* __restrict__ ru,
                                            const float* __restrict__ rvp,
                                            float* __restrict__ out) {
  int rc = blockIdx.x, b = blockIdx.y;  // (16, 4)
  __shared__ float vinv[512];
  __shared__ float uinv[32];
  int t = threadIdx.x;  // 512
  {
    float s = 0.f;
#pragma unroll
    for (int ic = 0; ic < 16; ++ic) s += rvp[ic * 2048 + b * NN + t];
    vinv[t] = 1.0f / s;
  }
  if (t < 32) uinv[t] = 1.0f / ru[b * NN + rc * 32 + t];
  __syncthreads();
  float vj = vinv[t];
  const float* Kp = Km + (size_t)(b * NN + rc * 32) * NN + t;
  float* op = out + (size_t)(b * NN + rc * 32) * NN + t;
#pragma unroll 4
  for (int m = 0; m < 32; ++m) {
    op[(size_t)m * NN] = Kp[(size_t)m * NN] * uinv[m] * vj;
  }
}

extern "C" void kernel_launch(void* const* d_in, const int* in_sizes, int n_in,
                              void* d_out, int out_size, void* d_ws, size_t ws_size,
                              hipStream_t stream) {
  (void)in_sizes; (void)n_in; (void)out_size; (void)ws_size;
  const float* X   = (const float*)d_in[0];
  const float* C   = (const float*)d_in[1];
  const float* W1  = (const float*)d_in[2];
  const float* b1  = (const float*)d_in[3];
  const float* W2  = (const float*)d_in[4];
  const float* b2  = (const float*)d_in[5];
  const float* Wg  = (const float*)d_in[6];
  const float* as_ = (const float*)d_in[7];
  const float* ad_ = (const float*)d_in[8];
  const float* bg  = (const float*)d_in[9];
  float* out = (float*)d_out;
  float* ws = (float*)d_ws;

  float* ha    = ws;                 // 262144
  float* hb    = ws + 262144;        // 262144
  float* Km    = ws + 524288;        // 1048576
  float* ru    = ws + 1572864;       // 2048
  float* xw    = ws + 1591296;       // 1048576
  float* ssT   = ws + 2639872;       // 8192
  float* sdT   = ws + 2648064;       // 8192
  float* x1    = ws + 2656256;       // 262144
  float* x2    = ws + 2918400;       // 262144
  float* rvpA  = ws + 3180544;       // 32768
  float* rvpB  = ws + 3246080;       // 32768
  float* adj   = out + 1048576;

  kA<<<dim3(64, 4), 128, 0, stream>>>(X, W1, b1, ha, hb, ru);
  kB<<<dim3(16, 16, 4), 256, 0, stream>>>(ha, hb, C, W1, W2, b2, Km, ru);
  // Sinkhorn chain with GAT/kF rider blocks packed into the first nodes
  nCcolG1f<<<dim3(80, 4), 512, 0, stream>>>(Km, ru, rvpA,
                                            X, Wg, as_, ad_, xw, ssT, sdT);
  nCrcG2v<<<dim3(80, 4), 512, 0, stream>>>(Km, rvpA, rvpB, ru,
                                           xw, ssT, sdT, bg, x1);              // it0 + G2v(L0)
  nCrcG1f<<<dim3(80, 4), 512, 0, stream>>>(Km, rvpB, rvpA, ru,
                                           x1, Wg + 65536, as_ + 512, ad_ + 512,
                                           xw, ssT, sdT);                      // it1 + G1f(L1)
  nCrcG2v<<<dim3(80, 4), 512, 0, stream>>>(Km, rvpA, rvpB, ru,
                                           xw, ssT, sdT, bg + 128, x2);        // it2 + G2v(L1)
  nCrcF<<<dim3(272, 4), 512, 0, stream>>>(Km, rvpB, rvpA, ru, x2, out);        // it3 + kF
  kCrc<<<dim3(16, 4), 512, 0, stream>>>(Km, rvpA, rvpB, ru);                   // it4
  kCrc<<<dim3(16, 4), 512, 0, stream>>>(Km, rvpB, rvpA, ru);                   // it5
  kCrc<<<dim3(16, 4), 512, 0, stream>>>(Km, rvpA, rvpB, ru);                   // it6
  kCrc<<<dim3(16, 4), 512, 0, stream>>>(Km, rvpB, rvpA, ru);                   // it7
  kCrc<<<dim3(16, 4), 512, 0, stream>>>(Km, rvpA, rvpB, ru);                   // it8
  kAdj<<<dim3(16, 4), 512, 0, stream>>>(Km, ru, rvpB, adj);
}